// Round 2
// baseline (2007.237 us; speedup 1.0000x reference)
//
#include <hip/hip_runtime.h>

#define NPTS 400000
#define KTAPS 9
#define BN_EPS 1e-5f

__device__ __forceinline__ float uint_as_float(unsigned int u) {
    union { unsigned int i; float f; } v; v.i = u; return v.f;
}

__device__ __forceinline__ unsigned short f32_to_bf16_rn(float f) {
    union { float f; unsigned int i; } v; v.f = f;
    unsigned int lsb = (v.i >> 16) & 1u;
    v.i += 0x7fffu + lsb;               // round-to-nearest-even
    return (unsigned short)(v.i >> 16);
}

// ---------------- Kernel A: two C=16 convs from fp32 features ----------------
// sc1 = BNReLU0(conv(feat, nbr13, w1));  t = BNReLU2(conv(feat, nbr31, w2))
// Outputs stored bf16 (32ch = 64B rows) for kernel B's gathers.

__device__ __forceinline__ void load_row16(const float* __restrict__ feat, int id,
                                           float* r, float* flag) {
    *flag = (id < NPTS) ? 1.f : 0.f;
    int s = (id < NPTS) ? id : 0;
    const float4* p = reinterpret_cast<const float4*>(feat + (size_t)s * 16);
    float4 a = p[0], b = p[1], c = p[2], d = p[3];
    r[0]=a.x; r[1]=a.y; r[2]=a.z; r[3]=a.w;
    r[4]=b.x; r[5]=b.y; r[6]=b.z; r[7]=b.w;
    r[8]=c.x; r[9]=c.y; r[10]=c.z; r[11]=c.w;
    r[12]=d.x; r[13]=d.y; r[14]=d.z; r[15]=d.w;
}

__device__ __forceinline__ void conv16_bn_store(
    const float* __restrict__ feat, const int* idx, const float* __restrict__ W,
    const float* __restrict__ g, const float* __restrict__ b,
    const float* __restrict__ m, const float* __restrict__ v,
    unsigned short* __restrict__ orow)
{
    float acc[32];
    #pragma unroll
    for (int o = 0; o < 32; ++o) acc[o] = 0.f;

    float cur[16], nxt[16], curf, nxtf;
    load_row16(feat, idx[0], cur, &curf);

    #pragma unroll 3
    for (int k = 0; k < KTAPS; ++k) {
        if (k + 1 < KTAPS) load_row16(feat, idx[k + 1], nxt, &nxtf);  // prefetch
        const float* wk = W + k * 16 * 32;
        #pragma unroll
        for (int c = 0; c < 16; ++c) {
            float fc = cur[c] * curf;
            const float* wr = wk + c * 32;
            #pragma unroll
            for (int o4 = 0; o4 < 8; ++o4) {
                float4 w4 = *reinterpret_cast<const float4*>(wr + o4 * 4);
                acc[o4*4+0] = fmaf(fc, w4.x, acc[o4*4+0]);
                acc[o4*4+1] = fmaf(fc, w4.y, acc[o4*4+1]);
                acc[o4*4+2] = fmaf(fc, w4.z, acc[o4*4+2]);
                acc[o4*4+3] = fmaf(fc, w4.w, acc[o4*4+3]);
            }
        }
        if (k + 1 < KTAPS) {
            #pragma unroll
            for (int c = 0; c < 16; ++c) cur[c] = nxt[c];
            curf = nxtf;
        }
    }

    // BN + ReLU + bf16 pack + 64B store
    unsigned int pack[16];
    #pragma unroll
    for (int j = 0; j < 16; ++j) {
        unsigned int lohi[2];
        #pragma unroll
        for (int h = 0; h < 2; ++h) {
            int o = 2 * j + h;
            float s = g[o] * rsqrtf(v[o] + BN_EPS);
            float bb = b[o] - m[o] * s;
            float y = fmaxf(fmaf(acc[o], s, bb), 0.f);
            lohi[h] = (unsigned int)f32_to_bf16_rn(y);
        }
        pack[j] = lohi[0] | (lohi[1] << 16);
    }
    uint4* op = reinterpret_cast<uint4*>(orow);
    op[0] = make_uint4(pack[0], pack[1], pack[2], pack[3]);
    op[1] = make_uint4(pack[4], pack[5], pack[6], pack[7]);
    op[2] = make_uint4(pack[8], pack[9], pack[10], pack[11]);
    op[3] = make_uint4(pack[12], pack[13], pack[14], pack[15]);
}

__global__ __launch_bounds__(256) void convA(
    const float* __restrict__ feat,
    const int* __restrict__ nbr13, const int* __restrict__ nbr31,
    const float* __restrict__ w1, const float* __restrict__ w2,
    const float* __restrict__ gamma, const float* __restrict__ beta,
    const float* __restrict__ mean, const float* __restrict__ var,
    unsigned short* __restrict__ sc1, unsigned short* __restrict__ tmain)
{
    int n = blockIdx.x * blockDim.x + threadIdx.x;
    if (n >= NPTS) return;

    int i13[KTAPS], i31[KTAPS];
    #pragma unroll
    for (int k = 0; k < KTAPS; ++k) i13[k] = nbr13[n * KTAPS + k];
    #pragma unroll
    for (int k = 0; k < KTAPS; ++k) i31[k] = nbr31[n * KTAPS + k];

    conv16_bn_store(feat, i13, w1, gamma + 0,  beta + 0,  mean + 0,  var + 0,
                    sc1 + (size_t)n * 32);
    conv16_bn_store(feat, i31, w2, gamma + 64, beta + 64, mean + 64, var + 64,
                    tmain + (size_t)n * 32);
}

// ---------------- Kernel B: two C=32 convs from bf16 tables ----------------
// out = BNReLU3(conv(t, nbr13, w3)) + BNReLU1(conv(sc1, nbr31, w12))

__device__ __forceinline__ void load_row32bf(const unsigned short* __restrict__ tab, int id,
                                             unsigned int* r, float* flag) {
    *flag = (id < NPTS) ? 1.f : 0.f;
    int s = (id < NPTS) ? id : 0;
    const uint4* p = reinterpret_cast<const uint4*>(tab + (size_t)s * 32);
    uint4 a = p[0], b = p[1], c = p[2], d = p[3];
    r[0]=a.x; r[1]=a.y; r[2]=a.z; r[3]=a.w;
    r[4]=b.x; r[5]=b.y; r[6]=b.z; r[7]=b.w;
    r[8]=c.x; r[9]=c.y; r[10]=c.z; r[11]=c.w;
    r[12]=d.x; r[13]=d.y; r[14]=d.z; r[15]=d.w;
}

__device__ __forceinline__ void conv32_bn(
    const unsigned short* __restrict__ tab, const int* idx, const float* __restrict__ W,
    const float* __restrict__ g, const float* __restrict__ b,
    const float* __restrict__ m, const float* __restrict__ v,
    float* __restrict__ y)
{
    float acc[32];
    #pragma unroll
    for (int o = 0; o < 32; ++o) acc[o] = 0.f;

    unsigned int cur[16], nxt[16];
    float curf, nxtf;
    load_row32bf(tab, idx[0], cur, &curf);

    #pragma unroll 1   // body ~1100 instrs; keep I$ footprint bounded
    for (int k = 0; k < KTAPS; ++k) {
        if (k + 1 < KTAPS) load_row32bf(tab, idx[k + 1], nxt, &nxtf);  // prefetch
        const float* wk = W + k * 32 * 32;
        #pragma unroll
        for (int p = 0; p < 16; ++p) {
            float flo = uint_as_float(cur[p] << 16) * curf;          // ch 2p
            float fhi = uint_as_float(cur[p] & 0xffff0000u) * curf;  // ch 2p+1
            const float* wlo = wk + (2 * p) * 32;
            const float* whi = wk + (2 * p + 1) * 32;
            #pragma unroll
            for (int o4 = 0; o4 < 8; ++o4) {
                float4 wa = *reinterpret_cast<const float4*>(wlo + o4 * 4);
                float4 wb = *reinterpret_cast<const float4*>(whi + o4 * 4);
                acc[o4*4+0] = fmaf(flo, wa.x, acc[o4*4+0]);
                acc[o4*4+1] = fmaf(flo, wa.y, acc[o4*4+1]);
                acc[o4*4+2] = fmaf(flo, wa.z, acc[o4*4+2]);
                acc[o4*4+3] = fmaf(flo, wa.w, acc[o4*4+3]);
                acc[o4*4+0] = fmaf(fhi, wb.x, acc[o4*4+0]);
                acc[o4*4+1] = fmaf(fhi, wb.y, acc[o4*4+1]);
                acc[o4*4+2] = fmaf(fhi, wb.z, acc[o4*4+2]);
                acc[o4*4+3] = fmaf(fhi, wb.w, acc[o4*4+3]);
            }
        }
        if (k + 1 < KTAPS) {
            #pragma unroll
            for (int p = 0; p < 16; ++p) cur[p] = nxt[p];
            curf = nxtf;
        }
    }

    #pragma unroll
    for (int o = 0; o < 32; ++o) {
        float s = g[o] * rsqrtf(v[o] + BN_EPS);
        float bb = b[o] - m[o] * s;
        y[o] = fmaxf(fmaf(acc[o], s, bb), 0.f);
    }
}

__global__ __launch_bounds__(256) void convB(
    const unsigned short* __restrict__ sc1, const unsigned short* __restrict__ tmain,
    const int* __restrict__ nbr13, const int* __restrict__ nbr31,
    const float* __restrict__ w12, const float* __restrict__ w3,
    const float* __restrict__ gamma, const float* __restrict__ beta,
    const float* __restrict__ mean, const float* __restrict__ var,
    float* __restrict__ out)
{
    int n = blockIdx.x * blockDim.x + threadIdx.x;
    if (n >= NPTS) return;

    int i13[KTAPS], i31[KTAPS];
    #pragma unroll
    for (int k = 0; k < KTAPS; ++k) i13[k] = nbr13[n * KTAPS + k];
    #pragma unroll
    for (int k = 0; k < KTAPS; ++k) i31[k] = nbr31[n * KTAPS + k];

    float ysc[32];
    conv32_bn(sc1, i31, w12, gamma + 32, beta + 32, mean + 32, var + 32, ysc);
    float ym[32];
    conv32_bn(tmain, i13, w3, gamma + 96, beta + 96, mean + 96, var + 96, ym);

    float* orow = out + (size_t)n * 32;
    #pragma unroll
    for (int o4 = 0; o4 < 8; ++o4) {
        float4 r;
        r.x = ym[o4*4+0] + ysc[o4*4+0];
        r.y = ym[o4*4+1] + ysc[o4*4+1];
        r.z = ym[o4*4+2] + ysc[o4*4+2];
        r.w = ym[o4*4+3] + ysc[o4*4+3];
        *reinterpret_cast<float4*>(orow + o4 * 4) = r;
    }
}

extern "C" void kernel_launch(void* const* d_in, const int* in_sizes, int n_in,
                              void* d_out, int out_size, void* d_ws, size_t ws_size,
                              hipStream_t stream) {
    const float* features = (const float*)d_in[0];
    const int*   nbr13    = (const int*)  d_in[1];
    const int*   nbr31    = (const int*)  d_in[2];
    const float* w1       = (const float*)d_in[3];
    const float* w12      = (const float*)d_in[4];
    const float* w2       = (const float*)d_in[5];
    const float* w3       = (const float*)d_in[6];
    const float* gamma    = (const float*)d_in[7];  // [4][32]
    const float* beta     = (const float*)d_in[8];
    const float* mean     = (const float*)d_in[9];
    const float* var      = (const float*)d_in[10];
    float* out = (float*)d_out;

    unsigned short* sc1   = (unsigned short*)d_ws;                       // [N][32] bf16
    unsigned short* tmain = (unsigned short*)d_ws + (size_t)NPTS * 32;   // [N][32] bf16

    dim3 grid((NPTS + 255) / 256), block(256);

    convA<<<grid, block, 0, stream>>>(features, nbr13, nbr31, w1, w2,
                                      gamma, beta, mean, var, sc1, tmain);
    convB<<<grid, block, 0, stream>>>(sc1, tmain, nbr13, nbr31, w12, w3,
                                      gamma, beta, mean, var, out);
}

// Round 3
// 392.154 us; speedup vs baseline: 5.1185x; 5.1185x over previous
//
#include <hip/hip_runtime.h>

#define NPTS 400000
#define KTAPS 9
#define BN_EPS 1e-5f

__device__ __forceinline__ float u2f(unsigned int u) {
    union { unsigned int i; float f; } v; v.i = u; return v.f;
}
__device__ __forceinline__ unsigned short f2bf(float f) {
    union { float f; unsigned int i; } v; v.f = f;
    v.i += 0x7fffu + ((v.i >> 16) & 1u);     // round-to-nearest-even
    return (unsigned short)(v.i >> 16);
}

// Load one 64B input row (C=16 f32 or C=32 bf16 -- both 16 dwords).
__device__ __forceinline__ void load_row64B(const void* __restrict__ inp, int id,
                                            unsigned int* r, float* flag) {
    *flag = (id < NPTS) ? 1.f : 0.f;
    int s = (id < NPTS) ? id : 0;
    const uint4* p = reinterpret_cast<const uint4*>((const char*)inp + (size_t)s * 64);
    uint4 a = p[0], b = p[1], c = p[2], d = p[3];
    r[0]=a.x;  r[1]=a.y;  r[2]=a.z;  r[3]=a.w;
    r[4]=b.x;  r[5]=b.y;  r[6]=b.z;  r[7]=b.w;
    r[8]=c.x;  r[9]=c.y;  r[10]=c.z; r[11]=c.w;
    r[12]=d.x; r[13]=d.y; r[14]=d.z; r[15]=d.w;
}

// One conv+BN+ReLU layer. 2 waves per 64 points: wave parity h picks output
// channels [h*16, h*16+16). Weight/BN addresses are wave-uniform (scalar loads).
template<bool IN_BF16, bool OUT_BF16, bool ADD>
__global__ __launch_bounds__(256) void gconv(
    const void* __restrict__ inp,    // [N][16] f32 or [N][32] bf16 (64B rows)
    const int*  __restrict__ nbr,    // [N][9]
    const float* __restrict__ W,     // [9][C][32]
    const float* __restrict__ gam, const float* __restrict__ bet,
    const float* __restrict__ mea, const float* __restrict__ var,
    const float* __restrict__ scadd, // f32 [N][32] addend (ADD only; may alias outp)
    void* __restrict__ outp)         // bf16 [N][32] or f32 [N][32]
{
    const int C = IN_BF16 ? 32 : 16;
    int t    = blockIdx.x * blockDim.x + threadIdx.x;
    int lane = t & 63;
    int wid  = t >> 6;
    int h = __builtin_amdgcn_readfirstlane(wid & 1);  // wave-uniform output half
    int n = (wid >> 1) * 64 + lane;                   // point id
    if (n >= NPTS) return;

    const int* nr = nbr + (size_t)n * KTAPS;

    float acc[16];
    #pragma unroll
    for (int i = 0; i < 16; ++i) acc[i] = 0.f;

    unsigned int cur[16], nxt[16];
    float curf, nxtf;
    load_row64B(inp, nr[0], cur, &curf);

    #pragma unroll 1
    for (int k = 0; k < KTAPS; ++k) {
        if (k + 1 < KTAPS) {
            int nid = nr[k + 1];
            load_row64B(inp, nid, nxt, &nxtf);        // prefetch under compute
        }
        if (IN_BF16) {
            #pragma unroll
            for (int p = 0; p < 16; ++p) {
                float flo = u2f(cur[p] << 16) * curf;          // ch 2p
                float fhi = u2f(cur[p] & 0xffff0000u) * curf;  // ch 2p+1
                const float* wr0 = W + (((size_t)k * 32 + 2 * p) << 5) + (h << 4);
                const float4* wp0 = reinterpret_cast<const float4*>(wr0);
                const float4* wp1 = reinterpret_cast<const float4*>(wr0 + 32);
                float4 a0 = wp0[0], a1 = wp0[1], a2 = wp0[2], a3 = wp0[3];
                float4 b0 = wp1[0], b1 = wp1[1], b2 = wp1[2], b3 = wp1[3];
                acc[0]  = fmaf(flo, a0.x, acc[0]);  acc[1]  = fmaf(flo, a0.y, acc[1]);
                acc[2]  = fmaf(flo, a0.z, acc[2]);  acc[3]  = fmaf(flo, a0.w, acc[3]);
                acc[4]  = fmaf(flo, a1.x, acc[4]);  acc[5]  = fmaf(flo, a1.y, acc[5]);
                acc[6]  = fmaf(flo, a1.z, acc[6]);  acc[7]  = fmaf(flo, a1.w, acc[7]);
                acc[8]  = fmaf(flo, a2.x, acc[8]);  acc[9]  = fmaf(flo, a2.y, acc[9]);
                acc[10] = fmaf(flo, a2.z, acc[10]); acc[11] = fmaf(flo, a2.w, acc[11]);
                acc[12] = fmaf(flo, a3.x, acc[12]); acc[13] = fmaf(flo, a3.y, acc[13]);
                acc[14] = fmaf(flo, a3.z, acc[14]); acc[15] = fmaf(flo, a3.w, acc[15]);
                acc[0]  = fmaf(fhi, b0.x, acc[0]);  acc[1]  = fmaf(fhi, b0.y, acc[1]);
                acc[2]  = fmaf(fhi, b0.z, acc[2]);  acc[3]  = fmaf(fhi, b0.w, acc[3]);
                acc[4]  = fmaf(fhi, b1.x, acc[4]);  acc[5]  = fmaf(fhi, b1.y, acc[5]);
                acc[6]  = fmaf(fhi, b1.z, acc[6]);  acc[7]  = fmaf(fhi, b1.w, acc[7]);
                acc[8]  = fmaf(fhi, b2.x, acc[8]);  acc[9]  = fmaf(fhi, b2.y, acc[9]);
                acc[10] = fmaf(fhi, b2.z, acc[10]); acc[11] = fmaf(fhi, b2.w, acc[11]);
                acc[12] = fmaf(fhi, b3.x, acc[12]); acc[13] = fmaf(fhi, b3.y, acc[13]);
                acc[14] = fmaf(fhi, b3.z, acc[14]); acc[15] = fmaf(fhi, b3.w, acc[15]);
            }
        } else {
            #pragma unroll
            for (int c = 0; c < 16; ++c) {
                float fc = u2f(cur[c]) * curf;
                const float* wr = W + (((size_t)k * 16 + c) << 5) + (h << 4);
                const float4* wp = reinterpret_cast<const float4*>(wr);
                float4 a0 = wp[0], a1 = wp[1], a2 = wp[2], a3 = wp[3];
                acc[0]  = fmaf(fc, a0.x, acc[0]);  acc[1]  = fmaf(fc, a0.y, acc[1]);
                acc[2]  = fmaf(fc, a0.z, acc[2]);  acc[3]  = fmaf(fc, a0.w, acc[3]);
                acc[4]  = fmaf(fc, a1.x, acc[4]);  acc[5]  = fmaf(fc, a1.y, acc[5]);
                acc[6]  = fmaf(fc, a1.z, acc[6]);  acc[7]  = fmaf(fc, a1.w, acc[7]);
                acc[8]  = fmaf(fc, a2.x, acc[8]);  acc[9]  = fmaf(fc, a2.y, acc[9]);
                acc[10] = fmaf(fc, a2.z, acc[10]); acc[11] = fmaf(fc, a2.w, acc[11]);
                acc[12] = fmaf(fc, a3.x, acc[12]); acc[13] = fmaf(fc, a3.y, acc[13]);
                acc[14] = fmaf(fc, a3.z, acc[14]); acc[15] = fmaf(fc, a3.w, acc[15]);
            }
        }
        if (k + 1 < KTAPS) {
            #pragma unroll
            for (int i = 0; i < 16; ++i) cur[i] = nxt[i];
            curf = nxtf;
        }
    }

    // BN (eval) + ReLU; BN params at wave-uniform addresses -> scalar path
    float y[16];
    #pragma unroll
    for (int j = 0; j < 16; ++j) {
        int o = h * 16 + j;
        float s  = gam[o] * rsqrtf(var[o] + BN_EPS);
        float bb = bet[o] - mea[o] * s;
        y[j] = fmaxf(fmaf(acc[j], s, bb), 0.f);
    }

    if (ADD) {
        const float4* ap = reinterpret_cast<const float4*>(scadd + (size_t)n * 32 + h * 16);
        float4 s0 = ap[0], s1 = ap[1], s2 = ap[2], s3 = ap[3];
        y[0]+=s0.x; y[1]+=s0.y; y[2]+=s0.z; y[3]+=s0.w;
        y[4]+=s1.x; y[5]+=s1.y; y[6]+=s1.z; y[7]+=s1.w;
        y[8]+=s2.x; y[9]+=s2.y; y[10]+=s2.z; y[11]+=s2.w;
        y[12]+=s3.x; y[13]+=s3.y; y[14]+=s3.z; y[15]+=s3.w;
    }

    if (OUT_BF16) {
        unsigned int pk[8];
        #pragma unroll
        for (int j = 0; j < 8; ++j)
            pk[j] = (unsigned int)f2bf(y[2 * j]) | ((unsigned int)f2bf(y[2 * j + 1]) << 16);
        uint4* op = reinterpret_cast<uint4*>((char*)outp + (size_t)n * 64 + h * 32);
        op[0] = make_uint4(pk[0], pk[1], pk[2], pk[3]);
        op[1] = make_uint4(pk[4], pk[5], pk[6], pk[7]);
    } else {
        float4* op = reinterpret_cast<float4*>((char*)outp + (size_t)n * 128 + h * 64);
        op[0] = make_float4(y[0],  y[1],  y[2],  y[3]);
        op[1] = make_float4(y[4],  y[5],  y[6],  y[7]);
        op[2] = make_float4(y[8],  y[9],  y[10], y[11]);
        op[3] = make_float4(y[12], y[13], y[14], y[15]);
    }
}

extern "C" void kernel_launch(void* const* d_in, const int* in_sizes, int n_in,
                              void* d_out, int out_size, void* d_ws, size_t ws_size,
                              hipStream_t stream) {
    const float* features = (const float*)d_in[0];
    const int*   nbr13    = (const int*)  d_in[1];
    const int*   nbr31    = (const int*)  d_in[2];
    const float* w1       = (const float*)d_in[3];
    const float* w12      = (const float*)d_in[4];
    const float* w2       = (const float*)d_in[5];
    const float* w3       = (const float*)d_in[6];
    const float* gamma    = (const float*)d_in[7];  // [4][32]
    const float* beta     = (const float*)d_in[8];
    const float* mean     = (const float*)d_in[9];
    const float* var      = (const float*)d_in[10];
    float* out = (float*)d_out;

    unsigned short* sc1   = (unsigned short*)d_ws;                       // [N][32] bf16
    unsigned short* tmain = (unsigned short*)d_ws + (size_t)NPTS * 32;   // [N][32] bf16

    // 2 waves (=2 output halves) per 64 points: 800k threads
    dim3 grid((2 * NPTS + 255) / 256), block(256);

    // sc1 = BNReLU0(conv16(features, nbr13, w1))           -> bf16 ws
    gconv<false, true, false><<<grid, block, 0, stream>>>(
        features, nbr13, w1, gamma + 0,  beta + 0,  mean + 0,  var + 0,  nullptr, sc1);
    // t   = BNReLU2(conv16(features, nbr31, w2))           -> bf16 ws
    gconv<false, true, false><<<grid, block, 0, stream>>>(
        features, nbr31, w2, gamma + 64, beta + 64, mean + 64, var + 64, nullptr, tmain);
    // sc  = BNReLU1(conv32(sc1, nbr31, w12))               -> f32 d_out (temp)
    gconv<true, false, false><<<grid, block, 0, stream>>>(
        sc1, nbr31, w12, gamma + 32, beta + 32, mean + 32, var + 32, nullptr, out);
    // out = BNReLU3(conv32(t, nbr13, w3)) + sc             (own-row read+write)
    gconv<true, false, true><<<grid, block, 0, stream>>>(
        tmain, nbr13, w3, gamma + 96, beta + 96, mean + 96, var + 96, out, out);
}

// Round 4
// 298.794 us; speedup vs baseline: 6.7178x; 1.3125x over previous
//
#include <hip/hip_runtime.h>

#define NPTS 400000
#define KTAPS 9
#define BN_EPS 1e-5f
#define NTILES (NPTS / 16)   // 25000 exact

typedef __attribute__((ext_vector_type(8))) short bf16x8;
typedef __attribute__((ext_vector_type(4))) float f32x4;

__device__ __forceinline__ unsigned short f2bf(float f) {
    union { float f; unsigned int i; } v; v.f = f;
    v.i += 0x7fffu + ((v.i >> 16) & 1u);   // round-to-nearest-even
    return (unsigned short)(v.i >> 16);
}

// ---- features f32 [N][16] -> bf16 [N][16] table (one row per thread) ----
__global__ __launch_bounds__(256) void cvt_feat(const float* __restrict__ feat,
                                                unsigned short* __restrict__ fb) {
    int n = blockIdx.x * 256 + threadIdx.x;
    if (n >= NPTS) return;
    const float4* p = reinterpret_cast<const float4*>(feat + (size_t)n * 16);
    float4 a = p[0], b = p[1], c = p[2], d = p[3];
    float v[16] = {a.x,a.y,a.z,a.w, b.x,b.y,b.z,b.w,
                   c.x,c.y,c.z,c.w, d.x,d.y,d.z,d.w};
    unsigned int pk[8];
    #pragma unroll
    for (int j = 0; j < 8; ++j)
        pk[j] = (unsigned int)f2bf(v[2*j]) | ((unsigned int)f2bf(v[2*j+1]) << 16);
    uint4* o = reinterpret_cast<uint4*>(fb + (size_t)n * 16);
    o[0] = make_uint4(pk[0], pk[1], pk[2], pk[3]);
    o[1] = make_uint4(pk[4], pk[5], pk[6], pk[7]);
}

// ---- gather + MFMA conv + BN + ReLU (+residual add) ----
// One 16-point tile per wave iteration. A: gathered bf16 rows, lane l reads
// 16B of row (l&15), k-chunk (l>>4). B: W bf16-packed in LDS with the SAME
// (lane,elem)->k map (so any HW K-permutation cancels). D: row=4*(l>>4)+r,
// col=l&15 (m89-verified). C=16 fuses two taps per MFMA (K=32 = 2 taps x 16ch).
template<int CIN, bool ADD, bool OUT_BF16>
__global__ __launch_bounds__(256) void conv_mfma(
    const unsigned short* __restrict__ tab,   // [N][CIN] bf16
    const int* __restrict__ nbr,              // [N][9], values in [0, N]
    const float* __restrict__ W,              // [9][CIN][32] f32
    const float* __restrict__ gam, const float* __restrict__ bet,
    const float* __restrict__ mea, const float* __restrict__ var,
    void* __restrict__ outp)                  // [N][32] bf16 table or f32 out
{
    constexpr int NFRAG = (CIN == 16) ? 5 : 9;          // MFMAs per n-block
    __shared__ __align__(16) unsigned short Bp[NFRAG * 2 * 512];  // 10/18 KB

    const int tid = threadIdx.x;
    // pack W -> LDS B-fragments: frag fb=(g,b), short index = fb*512 + l*8 + j
    for (int f = tid; f < NFRAG * 1024; f += 256) {
        int j = f & 7, l = (f >> 3) & 63, fb = f >> 9;
        int g = fb >> 1, b = fb & 1;
        int kk = 8 * (l >> 4) + j;                      // K position 0..31
        int tap, ch;
        if (CIN == 16) { tap = 2 * g + (kk >> 4); ch = kk & 15; }
        else           { tap = g;                 ch = kk;      }
        float w = (tap < KTAPS) ? W[((size_t)tap * CIN + ch) * 32 + b * 16 + (l & 15)] : 0.f;
        Bp[f] = f2bf(w);
    }
    __syncthreads();

    const int lane = tid & 63;
    const int lrow = lane & 15, lgrp = lane >> 4;
    const int nwaves = gridDim.x * 4;

    for (int tile = blockIdx.x * 4 + (tid >> 6); tile < NTILES; tile += nwaves) {
        const int tb = tile * 16;
        const int prow = tb + lrow;

        int idx[KTAPS];
        #pragma unroll
        for (int k = 0; k < KTAPS; ++k) idx[k] = nbr[(size_t)prow * KTAPS + k];

        // issue all gathers (independent -> deep MLP per wave)
        uint4 ga[NFRAG];
        #pragma unroll
        for (int q = 0; q < NFRAG; ++q) {
            int tsel, boff;
            if (CIN == 16) { tsel = 2 * q + (lgrp >> 1); if (tsel > 8) tsel = 8;
                             boff = (lgrp & 1) * 16; }
            else           { tsel = q; boff = lgrp * 16; }
            int id = idx[tsel];
            int s = (id < NPTS) ? id : 0;               // idx==N -> pad: zero below
            uint4 gv = *reinterpret_cast<const uint4*>(
                reinterpret_cast<const char*>(tab) + (size_t)s * (CIN * 2) + boff);
            if (id >= NPTS) gv = make_uint4(0u, 0u, 0u, 0u);
            ga[q] = gv;
        }

        f32x4 acc0 = {0.f, 0.f, 0.f, 0.f}, acc1 = {0.f, 0.f, 0.f, 0.f};
        #pragma unroll
        for (int q = 0; q < NFRAG; ++q) {
            bf16x8 a  = *reinterpret_cast<const bf16x8*>(&ga[q]);
            bf16x8 b0 = *reinterpret_cast<const bf16x8*>(&Bp[(2*q + 0) * 512 + lane * 8]);
            bf16x8 b1 = *reinterpret_cast<const bf16x8*>(&Bp[(2*q + 1) * 512 + lane * 8]);
            acc0 = __builtin_amdgcn_mfma_f32_16x16x32_bf16(a, b0, acc0, 0, 0, 0);
            acc1 = __builtin_amdgcn_mfma_f32_16x16x32_bf16(a, b1, acc1, 0, 0, 0);
        }

        // epilogue: D[row=4*lgrp+r][col=b*16+lrow]; BN+ReLU (+add), store
        #pragma unroll
        for (int b = 0; b < 2; ++b) {
            const int o = b * 16 + lrow;
            const float s  = gam[o] * rsqrtf(var[o] + BN_EPS);
            const float bb = bet[o] - mea[o] * s;
            const f32x4 a = (b == 0) ? acc0 : acc1;
            #pragma unroll
            for (int r = 0; r < 4; ++r) {
                const int m = tb + 4 * lgrp + r;
                float y = fmaxf(fmaf(a[r], s, bb), 0.f);
                if (OUT_BF16) {
                    ((unsigned short*)outp)[(size_t)m * 32 + o] = f2bf(y);
                } else {
                    float* po = (float*)outp + (size_t)m * 32 + o;
                    if (ADD) y += *po;                 // own row: race-free RMW
                    *po = y;
                }
            }
        }
    }
}

extern "C" void kernel_launch(void* const* d_in, const int* in_sizes, int n_in,
                              void* d_out, int out_size, void* d_ws, size_t ws_size,
                              hipStream_t stream) {
    const float* features = (const float*)d_in[0];
    const int*   nbr13    = (const int*)  d_in[1];
    const int*   nbr31    = (const int*)  d_in[2];
    const float* w1       = (const float*)d_in[3];
    const float* w12      = (const float*)d_in[4];
    const float* w2       = (const float*)d_in[5];
    const float* w3       = (const float*)d_in[6];
    const float* gamma    = (const float*)d_in[7];  // [4][32]
    const float* beta     = (const float*)d_in[8];
    const float* mean     = (const float*)d_in[9];
    const float* var      = (const float*)d_in[10];
    float* out = (float*)d_out;

    unsigned short* sc1 = (unsigned short*)d_ws;                       // [N][32] bf16
    unsigned short* tmn = (unsigned short*)d_ws + (size_t)NPTS * 32;   // [N][32] bf16
    unsigned short* fb  = (unsigned short*)d_out;  // [N][16] bf16, dead before f32 writes

    cvt_feat<<<(NPTS + 255) / 256, 256, 0, stream>>>(features, fb);

    // sc1 = BNReLU0(conv16(featb, nbr13, w1))
    conv_mfma<16, false, true><<<2048, 256, 0, stream>>>(
        fb, nbr13, w1, gamma + 0,  beta + 0,  mean + 0,  var + 0,  sc1);
    // t   = BNReLU2(conv16(featb, nbr31, w2))
    conv_mfma<16, false, true><<<2048, 256, 0, stream>>>(
        fb, nbr31, w2, gamma + 64, beta + 64, mean + 64, var + 64, tmn);
    // out = BNReLU3(conv32(t, nbr13, w3))        (overwrites fb region - fb dead)
    conv_mfma<32, false, false><<<2048, 256, 0, stream>>>(
        tmn, nbr13, w3, gamma + 96, beta + 96, mean + 96, var + 96, out);
    // out += BNReLU1(conv32(sc1, nbr31, w12))    (residual, own-row RMW)
    conv_mfma<32, true, false><<<2048, 256, 0, stream>>>(
        sc1, nbr31, w12, gamma + 32, beta + 32, mean + 32, var + 32, out);
}

// Round 5
// 262.554 us; speedup vs baseline: 7.6450x; 1.1380x over previous
//
#include <hip/hip_runtime.h>

#define NPTS 400000
#define KTAPS 9
#define BN_EPS 1e-5f
#define NTILES (NPTS / 16)   // 25000 exact

typedef __attribute__((ext_vector_type(8))) short bf16x8;
typedef __attribute__((ext_vector_type(4))) float f32x4;

__device__ __forceinline__ unsigned short f2bf(float f) {
    union { float f; unsigned int i; } v; v.f = f;
    v.i += 0x7fffu + ((v.i >> 16) & 1u);   // round-to-nearest-even
    return (unsigned short)(v.i >> 16);
}

// ---- features f32 [N][16] -> bf16 [N][16] table ----
__global__ __launch_bounds__(256) void cvt_feat(const float* __restrict__ feat,
                                                unsigned short* __restrict__ fb) {
    int n = blockIdx.x * 256 + threadIdx.x;
    if (n >= NPTS) return;
    const float4* p = reinterpret_cast<const float4*>(feat + (size_t)n * 16);
    float4 a = p[0], b = p[1], c = p[2], d = p[3];
    float v[16] = {a.x,a.y,a.z,a.w, b.x,b.y,b.z,b.w,
                   c.x,c.y,c.z,c.w, d.x,d.y,d.z,d.w};
    unsigned int pk[8];
    #pragma unroll
    for (int j = 0; j < 8; ++j)
        pk[j] = (unsigned int)f2bf(v[2*j]) | ((unsigned int)f2bf(v[2*j+1]) << 16);
    uint4* o = reinterpret_cast<uint4*>(fb + (size_t)n * 16);
    o[0] = make_uint4(pk[0], pk[1], pk[2], pk[3]);
    o[1] = make_uint4(pk[4], pk[5], pk[6], pk[7]);
}

// ---- one-shot packer: 4 weight tables -> bf16 B-fragments, BN -> (s,b) ----
// pw layout (shorts): w1 @0 (5120), w2 @5120, w12 @10240 (9216), w3 @19456; total 28672
// sbf: [4][32] float2 as flat floats, BN row order 0..3
__global__ __launch_bounds__(256) void pack_all(
    const float* __restrict__ w1, const float* __restrict__ w2,
    const float* __restrict__ w12, const float* __restrict__ w3,
    const float* __restrict__ gamma, const float* __restrict__ beta,
    const float* __restrict__ mean, const float* __restrict__ var,
    unsigned short* __restrict__ pw, float* __restrict__ sbf)
{
    int t = blockIdx.x * 256 + threadIdx.x;
    if (t < 28672) {
        const float* W; int CIN, f;
        if      (t < 5120)  { W = w1;  CIN = 16; f = t; }
        else if (t < 10240) { W = w2;  CIN = 16; f = t - 5120; }
        else if (t < 19456) { W = w12; CIN = 32; f = t - 10240; }
        else                { W = w3;  CIN = 32; f = t - 19456; }
        int j = f & 7, l = (f >> 3) & 63, fb = f >> 9;
        int g = fb >> 1, b = fb & 1;
        int kk = 8 * (l >> 4) + j;
        int tap, ch;
        if (CIN == 16) { tap = 2 * g + (kk >> 4); ch = kk & 15; }
        else           { tap = g;                 ch = kk;      }
        float w = (tap < KTAPS) ? W[((size_t)(tap * CIN + ch)) * 32 + b * 16 + (l & 15)] : 0.f;
        pw[t] = f2bf(w);
    } else if (t < 28672 + 128) {
        int r = t - 28672;                      // r = bnrow*32 + o
        float s  = gamma[r] * rsqrtf(var[r] + BN_EPS);
        float bb = beta[r] - mean[r] * s;
        sbf[2 * r]     = s;
        sbf[2 * r + 1] = bb;
    }
}

// ---- gather + MFMA conv + BN + ReLU (+residual add) ----
// Exactly one 16-point tile per wave (6250 blocks x 4 waves = 25000 tiles).
// idx loads issue before the LDS W-fill; the barrier's vmcnt(0) drains both.
template<int CIN, bool ADD, bool OUT_BF16>
__global__ __launch_bounds__(256) void conv_mfma(
    const unsigned short* __restrict__ tab,   // [N][CIN] bf16
    const int* __restrict__ nbr,              // [N][9]
    const float* __restrict__ Wf32,           // fallback pack source
    const unsigned short* __restrict__ pW,    // packed frags (or null)
    const float* __restrict__ sbf,            // packed (s,b)[32] (or null)
    const float* __restrict__ gam, const float* __restrict__ bet,
    const float* __restrict__ mea, const float* __restrict__ var,
    void* __restrict__ outp)
{
    constexpr int NFRAG = (CIN == 16) ? 5 : 9;
    __shared__ __align__(16) unsigned short Bp[NFRAG * 1024];  // 10/18 KB
    __shared__ float2 SB[32];

    const int tid  = threadIdx.x;
    const int lane = tid & 63;
    const int lrow = lane & 15, lgrp = lane >> 4;
    const int tile = blockIdx.x * 4 + (tid >> 6);   // < 25000 exact
    const int tb   = tile * 16;
    const int prow = tb + lrow;

    // (1) issue idx loads first — latency hides under W staging
    int idx[KTAPS];
    #pragma unroll
    for (int k = 0; k < KTAPS; ++k) idx[k] = nbr[(size_t)prow * KTAPS + k];

    // (2) stage B-fragments into LDS
    if (pW != nullptr) {
        #pragma unroll
        for (int i = tid; i < NFRAG * 128; i += 256)
            reinterpret_cast<uint4*>(Bp)[i] = reinterpret_cast<const uint4*>(pW)[i];
        if (tid < 32) SB[tid] = reinterpret_cast<const float2*>(sbf)[tid];
    } else {
        for (int f = tid; f < NFRAG * 1024; f += 256) {
            int j = f & 7, l = (f >> 3) & 63, fb = f >> 9;
            int g = fb >> 1, b = fb & 1;
            int kk = 8 * (l >> 4) + j;
            int tap, ch;
            if (CIN == 16) { tap = 2 * g + (kk >> 4); ch = kk & 15; }
            else           { tap = g;                 ch = kk;      }
            float w = (tap < KTAPS) ? Wf32[((size_t)(tap * CIN + ch)) * 32 + b * 16 + (l & 15)] : 0.f;
            Bp[f] = f2bf(w);
        }
        if (tid < 32) {
            float s  = gam[tid] * rsqrtf(var[tid] + BN_EPS);
            float bb = bet[tid] - mea[tid] * s;
            SB[tid] = make_float2(s, bb);
        }
    }
    __syncthreads();

    // (3) gathers — all independent, deep MLP
    uint4 ga[NFRAG];
    #pragma unroll
    for (int q = 0; q < NFRAG; ++q) {
        int tsel, boff;
        if (CIN == 16) { tsel = 2 * q + (lgrp >> 1); if (tsel > 8) tsel = 8;
                         boff = (lgrp & 1) * 16; }
        else           { tsel = q; boff = lgrp * 16; }
        int id = idx[tsel];
        int s = (id < NPTS) ? id : 0;
        uint4 gv = *reinterpret_cast<const uint4*>(
            reinterpret_cast<const char*>(tab) + (size_t)s * (CIN * 2) + boff);
        if (id >= NPTS) gv = make_uint4(0u, 0u, 0u, 0u);
        ga[q] = gv;
    }

    // (4) MFMA
    f32x4 acc0 = {0.f, 0.f, 0.f, 0.f}, acc1 = {0.f, 0.f, 0.f, 0.f};
    #pragma unroll
    for (int q = 0; q < NFRAG; ++q) {
        bf16x8 a  = *reinterpret_cast<const bf16x8*>(&ga[q]);
        bf16x8 b0 = *reinterpret_cast<const bf16x8*>(&Bp[(2*q + 0) * 512 + lane * 8]);
        bf16x8 b1 = *reinterpret_cast<const bf16x8*>(&Bp[(2*q + 1) * 512 + lane * 8]);
        acc0 = __builtin_amdgcn_mfma_f32_16x16x32_bf16(a, b0, acc0, 0, 0, 0);
        acc1 = __builtin_amdgcn_mfma_f32_16x16x32_bf16(a, b1, acc1, 0, 0, 0);
    }

    // (5) epilogue: D[row=4*lgrp+r][col=b*16+lrow]
    #pragma unroll
    for (int b = 0; b < 2; ++b) {
        const int o = b * 16 + lrow;
        const float2 sv = SB[o];
        const f32x4 a = (b == 0) ? acc0 : acc1;
        #pragma unroll
        for (int r = 0; r < 4; ++r) {
            const int m = tb + 4 * lgrp + r;
            float y = fmaxf(fmaf(a[r], sv.x, sv.y), 0.f);
            if (OUT_BF16) {
                ((unsigned short*)outp)[(size_t)m * 32 + o] = f2bf(y);
            } else {
                float* po = (float*)outp + (size_t)m * 32 + o;
                if (ADD) y += *po;                 // own row: race-free RMW
                *po = y;
            }
        }
    }
}

extern "C" void kernel_launch(void* const* d_in, const int* in_sizes, int n_in,
                              void* d_out, int out_size, void* d_ws, size_t ws_size,
                              hipStream_t stream) {
    const float* features = (const float*)d_in[0];
    const int*   nbr13    = (const int*)  d_in[1];
    const int*   nbr31    = (const int*)  d_in[2];
    const float* w1       = (const float*)d_in[3];
    const float* w12      = (const float*)d_in[4];
    const float* w2       = (const float*)d_in[5];
    const float* w3       = (const float*)d_in[6];
    const float* gamma    = (const float*)d_in[7];  // [4][32]
    const float* beta     = (const float*)d_in[8];
    const float* mean     = (const float*)d_in[9];
    const float* var      = (const float*)d_in[10];
    float* out = (float*)d_out;

    const size_t tabShorts = (size_t)NPTS * 32;          // 12.8M shorts = 25.6 MB
    unsigned short* sc1 = (unsigned short*)d_ws;
    unsigned short* tmn = sc1 + tabShorts;
    unsigned short* fb  = (unsigned short*)d_out;        // [N][16] bf16, dead before f32 writes

    // packed weights + BN, if scratch has room (2*25.6MB + 58KB + 1KB)
    unsigned short* pw  = nullptr;
    float*          sbf = nullptr;
    const size_t need = 2 * tabShorts * 2 + 28672 * 2 + 256 * 4;
    if (ws_size >= need) {
        pw  = tmn + tabShorts;
        sbf = (float*)(pw + 28672);
        pack_all<<<113, 256, 0, stream>>>(w1, w2, w12, w3, gamma, beta, mean, var, pw, sbf);
    }

    cvt_feat<<<(NPTS + 255) / 256, 256, 0, stream>>>(features, fb);

    const unsigned short* pw1  = pw;
    const unsigned short* pw2  = pw ? pw + 5120  : nullptr;
    const unsigned short* pw12 = pw ? pw + 10240 : nullptr;
    const unsigned short* pw3  = pw ? pw + 19456 : nullptr;

    dim3 grid(NTILES / 4), block(256);   // 6250 blocks, 1 tile per wave

    // sc1 = BNReLU0(conv16(fb, nbr13, w1))
    conv_mfma<16, false, true><<<grid, block, 0, stream>>>(
        fb, nbr13, w1, pw1, sbf ? sbf + 0 : nullptr,
        gamma + 0,  beta + 0,  mean + 0,  var + 0,  sc1);
    // t   = BNReLU2(conv16(fb, nbr31, w2))
    conv_mfma<16, false, true><<<grid, block, 0, stream>>>(
        fb, nbr31, w2, pw2, sbf ? sbf + 128 : nullptr,
        gamma + 64, beta + 64, mean + 64, var + 64, tmn);
    // out = BNReLU3(conv32(t, nbr13, w3))        (overwrites fb region — fb dead)
    conv_mfma<32, false, false><<<grid, block, 0, stream>>>(
        tmn, nbr13, w3, pw3, sbf ? sbf + 192 : nullptr,
        gamma + 96, beta + 96, mean + 96, var + 96, out);
    // out += BNReLU1(conv32(sc1, nbr31, w12))    (residual, own-row RMW)
    conv_mfma<32, true, false><<<grid, block, 0, stream>>>(
        sc1, nbr31, w12, pw12, sbf ? sbf + 64 : nullptr,
        gamma + 32, beta + 32, mean + 32, var + 32, out);
}

// Round 7
// 251.305 us; speedup vs baseline: 7.9873x; 1.0448x over previous
//
#include <hip/hip_runtime.h>

#define NPTS 400000
#define KTAPS 9
#define BN_EPS 1e-5f
#define NTILES (NPTS / 16)   // 25000 exact

typedef __attribute__((ext_vector_type(8))) short bf16x8;
typedef __attribute__((ext_vector_type(4))) float f32x4;

__device__ __forceinline__ unsigned short f2bf(float f) {
    union { float f; unsigned int i; } v; v.f = f;
    v.i += 0x7fffu + ((v.i >> 16) & 1u);   // round-to-nearest-even
    return (unsigned short)(v.i >> 16);
}

// ---- features f32 [N][16] -> bf16 [N][16] table ----
__global__ __launch_bounds__(256) void cvt_feat(const float* __restrict__ feat,
                                                unsigned short* __restrict__ fb) {
    int n = blockIdx.x * 256 + threadIdx.x;
    if (n >= NPTS) return;
    const float4* p = reinterpret_cast<const float4*>(feat + (size_t)n * 16);
    float4 a = p[0], b = p[1], c = p[2], d = p[3];
    float v[16] = {a.x,a.y,a.z,a.w, b.x,b.y,b.z,b.w,
                   c.x,c.y,c.z,c.w, d.x,d.y,d.z,d.w};
    unsigned int pk[8];
    #pragma unroll
    for (int j = 0; j < 8; ++j)
        pk[j] = (unsigned int)f2bf(v[2*j]) | ((unsigned int)f2bf(v[2*j+1]) << 16);
    uint4* o = reinterpret_cast<uint4*>(fb + (size_t)n * 16);
    o[0] = make_uint4(pk[0], pk[1], pk[2], pk[3]);
    o[1] = make_uint4(pk[4], pk[5], pk[6], pk[7]);
}

// ---- one-shot packer: 4 weight tables -> bf16 B-fragments, BN -> (s,b) ----
// pw (shorts): w1@0 (5120), w2@5120 (5120), w12@10240 (9216), w3@19456 (9216)
// sbf: [4][32] float2 flat, BN rows 0..3
__global__ __launch_bounds__(256) void pack_all(
    const float* __restrict__ w1, const float* __restrict__ w2,
    const float* __restrict__ w12, const float* __restrict__ w3,
    const float* __restrict__ gamma, const float* __restrict__ beta,
    const float* __restrict__ mean, const float* __restrict__ var,
    unsigned short* __restrict__ pw, float* __restrict__ sbf)
{
    int t = blockIdx.x * 256 + threadIdx.x;
    if (t < 28672) {
        const float* W; int CIN, f;
        if      (t < 5120)  { W = w1;  CIN = 16; f = t; }
        else if (t < 10240) { W = w2;  CIN = 16; f = t - 5120; }
        else if (t < 19456) { W = w12; CIN = 32; f = t - 10240; }
        else                { W = w3;  CIN = 32; f = t - 19456; }
        int j = f & 7, l = (f >> 3) & 63, fb = f >> 9;
        int g = fb >> 1, b = fb & 1;
        int kk = 8 * (l >> 4) + j;
        int tap, ch;
        if (CIN == 16) { tap = 2 * g + (kk >> 4); ch = kk & 15; }
        else           { tap = g;                 ch = kk;      }
        float w = (tap < KTAPS) ? W[((size_t)(tap * CIN + ch)) * 32 + b * 16 + (l & 15)] : 0.f;
        pw[t] = f2bf(w);
    } else if (t < 28672 + 128) {
        int r = t - 28672;
        float s  = gamma[r] * rsqrtf(var[r] + BN_EPS);
        float bb = beta[r] - mean[r] * s;
        sbf[2 * r]     = s;
        sbf[2 * r + 1] = bb;
    }
}

__device__ __forceinline__ uint4 gather16(const char* __restrict__ base, int id,
                                          int rowBytes, int boff) {
    int s = (id < NPTS) ? id : 0;
    uint4 v = *reinterpret_cast<const uint4*>(base + (size_t)s * rowBytes + boff);
    if (id >= NPTS) v = make_uint4(0u, 0u, 0u, 0u);
    return v;
}

// fallback in-kernel packer for one CIN=16 or CIN=32 table into LDS
__device__ __forceinline__ void pack_lds(unsigned short* Bp, const float* W,
                                         int CIN, int nshorts, int tid) {
    for (int f = tid; f < nshorts; f += 256) {
        int j = f & 7, l = (f >> 3) & 63, fb = f >> 9;
        int g = fb >> 1, b = fb & 1;
        int kk = 8 * (l >> 4) + j;
        int tap, ch;
        if (CIN == 16) { tap = 2 * g + (kk >> 4); ch = kk & 15; }
        else           { tap = g;                 ch = kk;      }
        float w = (tap < KTAPS) ? W[((size_t)(tap * CIN + ch)) * 32 + b * 16 + (l & 15)] : 0.f;
        Bp[f] = f2bf(w);
    }
}

// ---- Kernel A: conv1 (fb,nbr13,w1,BN0 -> sc1) + conv2 (fb,nbr31,w2,BN2 -> tmn) ----
// One 16-pt tile per wave; 10 gathers in flight.
__global__ __launch_bounds__(256) void convA(
    const unsigned short* __restrict__ fb,
    const int* __restrict__ nbr13, const int* __restrict__ nbr31,
    const float* __restrict__ w1f, const float* __restrict__ w2f,
    const unsigned short* __restrict__ pW, const float* __restrict__ sbf,
    const float* __restrict__ gamma, const float* __restrict__ beta,
    const float* __restrict__ mean, const float* __restrict__ var,
    unsigned short* __restrict__ sc1, unsigned short* __restrict__ tmn)
{
    __shared__ __align__(16) unsigned short Bp[10240];  // w1 frags | w2 frags
    __shared__ float2 SB[64];                           // [0..31]=BN0, [32..63]=BN2

    const int tid  = threadIdx.x;
    const int lane = tid & 63;
    const int lrow = lane & 15, lgrp = lane >> 4;
    const int tile = blockIdx.x * 4 + (tid >> 6);
    const int tb   = tile * 16;
    const int prow = tb + lrow;

    int i13[KTAPS], i31[KTAPS];
    #pragma unroll
    for (int k = 0; k < KTAPS; ++k) i13[k] = nbr13[(size_t)prow * KTAPS + k];
    #pragma unroll
    for (int k = 0; k < KTAPS; ++k) i31[k] = nbr31[(size_t)prow * KTAPS + k];

    if (pW != nullptr) {
        // Bp = 10240 shorts = 1280 uint4 (w1: 640, w2: 640)
        #pragma unroll
        for (int i = tid; i < 1280; i += 256)
            reinterpret_cast<uint4*>(Bp)[i] = reinterpret_cast<const uint4*>(pW)[i];
        if (tid < 64)
            SB[tid] = reinterpret_cast<const float2*>(sbf)[(tid < 32) ? tid : tid + 32];
    } else {
        pack_lds(Bp, w1f, 16, 5120, tid);
        pack_lds(Bp + 5120, w2f, 16, 5120, tid);
        if (tid < 64) {
            int row = (tid < 32) ? 0 : 2, o = tid & 31;
            float s  = gamma[row*32+o] * rsqrtf(var[row*32+o] + BN_EPS);
            float bb = beta[row*32+o] - mean[row*32+o] * s;
            SB[tid] = make_float2(s, bb);
        }
    }
    __syncthreads();

    // 10 independent gathers (fb rows are 32B)
    uint4 g1[5], g2[5];
    #pragma unroll
    for (int q = 0; q < 5; ++q) {
        int tsel = 2 * q + (lgrp >> 1); if (tsel > 8) tsel = 8;
        int boff = (lgrp & 1) * 16;
        g1[q] = gather16((const char*)fb, i13[tsel], 32, boff);
        g2[q] = gather16((const char*)fb, i31[tsel], 32, boff);
    }

    f32x4 a10 = {0,0,0,0}, a11 = {0,0,0,0}, a20 = {0,0,0,0}, a21 = {0,0,0,0};
    #pragma unroll
    for (int q = 0; q < 5; ++q) {
        bf16x8 x1 = *reinterpret_cast<const bf16x8*>(&g1[q]);
        bf16x8 x2 = *reinterpret_cast<const bf16x8*>(&g2[q]);
        bf16x8 b10 = *reinterpret_cast<const bf16x8*>(&Bp[(2*q+0)*512 + lane*8]);
        bf16x8 b11 = *reinterpret_cast<const bf16x8*>(&Bp[(2*q+1)*512 + lane*8]);
        bf16x8 b20 = *reinterpret_cast<const bf16x8*>(&Bp[5120 + (2*q+0)*512 + lane*8]);
        bf16x8 b21 = *reinterpret_cast<const bf16x8*>(&Bp[5120 + (2*q+1)*512 + lane*8]);
        a10 = __builtin_amdgcn_mfma_f32_16x16x32_bf16(x1, b10, a10, 0, 0, 0);
        a11 = __builtin_amdgcn_mfma_f32_16x16x32_bf16(x1, b11, a11, 0, 0, 0);
        a20 = __builtin_amdgcn_mfma_f32_16x16x32_bf16(x2, b20, a20, 0, 0, 0);
        a21 = __builtin_amdgcn_mfma_f32_16x16x32_bf16(x2, b21, a21, 0, 0, 0);
    }

    #pragma unroll
    for (int b = 0; b < 2; ++b) {
        const int o = b * 16 + lrow;
        const float2 s0 = SB[o];        // BN row 0 (sc1)
        const float2 s2 = SB[32 + o];   // BN row 2 (tmn)
        const f32x4 v1 = (b == 0) ? a10 : a11;
        const f32x4 v2 = (b == 0) ? a20 : a21;
        #pragma unroll
        for (int r = 0; r < 4; ++r) {
            const int m = tb + 4 * lgrp + r;
            sc1[(size_t)m * 32 + o] = f2bf(fmaxf(fmaf(v1[r], s0.x, s0.y), 0.f));
            tmn[(size_t)m * 32 + o] = f2bf(fmaxf(fmaf(v2[r], s2.x, s2.y), 0.f));
        }
    }
}

// ---- Kernel B: out = BNReLU3(conv(tmn,nbr13,w3)) + BNReLU1(conv(sc1,nbr31,w12)) ----
// 18 gathers in flight; no RMW on d_out.
__global__ __launch_bounds__(256) void convB(
    const unsigned short* __restrict__ sc1, const unsigned short* __restrict__ tmn,
    const int* __restrict__ nbr13, const int* __restrict__ nbr31,
    const float* __restrict__ w12f, const float* __restrict__ w3f,
    const unsigned short* __restrict__ pW, const float* __restrict__ sbf,
    const float* __restrict__ gamma, const float* __restrict__ beta,
    const float* __restrict__ mean, const float* __restrict__ var,
    float* __restrict__ out)
{
    __shared__ __align__(16) unsigned short Bp[18432];  // w12 frags | w3 frags
    __shared__ float2 SB[64];                           // [0..31]=BN1, [32..63]=BN3

    const int tid  = threadIdx.x;
    const int lane = tid & 63;
    const int lrow = lane & 15, lgrp = lane >> 4;
    const int tile = blockIdx.x * 4 + (tid >> 6);
    const int tb   = tile * 16;
    const int prow = tb + lrow;

    int i13[KTAPS], i31[KTAPS];
    #pragma unroll
    for (int k = 0; k < KTAPS; ++k) i13[k] = nbr13[(size_t)prow * KTAPS + k];
    #pragma unroll
    for (int k = 0; k < KTAPS; ++k) i31[k] = nbr31[(size_t)prow * KTAPS + k];

    if (pW != nullptr) {
        // Bp = 18432 shorts = 2304 uint4 (w12: 1152, w3: 1152)
        #pragma unroll
        for (int i = tid; i < 2304; i += 256)
            reinterpret_cast<uint4*>(Bp)[i] =
                reinterpret_cast<const uint4*>(pW + 10240)[i];
        if (tid < 64)
            SB[tid] = reinterpret_cast<const float2*>(sbf)[32 + ((tid < 32) ? tid : tid + 32)];
    } else {
        pack_lds(Bp, w12f, 32, 9216, tid);
        pack_lds(Bp + 9216, w3f, 32, 9216, tid);
        if (tid < 64) {
            int row = (tid < 32) ? 1 : 3, o = tid & 31;
            float s  = gamma[row*32+o] * rsqrtf(var[row*32+o] + BN_EPS);
            float bb = beta[row*32+o] - mean[row*32+o] * s;
            SB[tid] = make_float2(s, bb);
        }
    }
    __syncthreads();

    // 18 independent gathers (table rows are 64B)
    const int boff = lgrp * 16;
    uint4 gs[KTAPS], gt[KTAPS];
    #pragma unroll
    for (int q = 0; q < KTAPS; ++q) gs[q] = gather16((const char*)sc1, i31[q], 64, boff);
    #pragma unroll
    for (int q = 0; q < KTAPS; ++q) gt[q] = gather16((const char*)tmn, i13[q], 64, boff);

    f32x4 s0 = {0,0,0,0}, s1 = {0,0,0,0}, t0 = {0,0,0,0}, t1 = {0,0,0,0};
    #pragma unroll
    for (int q = 0; q < KTAPS; ++q) {
        bf16x8 xs = *reinterpret_cast<const bf16x8*>(&gs[q]);
        bf16x8 xt = *reinterpret_cast<const bf16x8*>(&gt[q]);
        bf16x8 bs0 = *reinterpret_cast<const bf16x8*>(&Bp[(2*q+0)*512 + lane*8]);
        bf16x8 bs1 = *reinterpret_cast<const bf16x8*>(&Bp[(2*q+1)*512 + lane*8]);
        bf16x8 bt0 = *reinterpret_cast<const bf16x8*>(&Bp[9216 + (2*q+0)*512 + lane*8]);
        bf16x8 bt1 = *reinterpret_cast<const bf16x8*>(&Bp[9216 + (2*q+1)*512 + lane*8]);
        s0 = __builtin_amdgcn_mfma_f32_16x16x32_bf16(xs, bs0, s0, 0, 0, 0);
        s1 = __builtin_amdgcn_mfma_f32_16x16x32_bf16(xs, bs1, s1, 0, 0, 0);
        t0 = __builtin_amdgcn_mfma_f32_16x16x32_bf16(xt, bt0, t0, 0, 0, 0);
        t1 = __builtin_amdgcn_mfma_f32_16x16x32_bf16(xt, bt1, t1, 0, 0, 0);
    }

    #pragma unroll
    for (int b = 0; b < 2; ++b) {
        const int o = b * 16 + lrow;
        const float2 c1 = SB[o];        // BN row 1 (sc path, w12)
        const float2 c3 = SB[32 + o];   // BN row 3 (main path, w3)
        const f32x4 vs = (b == 0) ? s0 : s1;
        const f32x4 vt = (b == 0) ? t0 : t1;
        #pragma unroll
        for (int r = 0; r < 4; ++r) {
            const int m = tb + 4 * lgrp + r;
            float ys = fmaxf(fmaf(vs[r], c1.x, c1.y), 0.f);
            float yt = fmaxf(fmaf(vt[r], c3.x, c3.y), 0.f);
            out[(size_t)m * 32 + o] = ys + yt;
        }
    }
}

extern "C" void kernel_launch(void* const* d_in, const int* in_sizes, int n_in,
                              void* d_out, int out_size, void* d_ws, size_t ws_size,
                              hipStream_t stream) {
    const float* features = (const float*)d_in[0];
    const int*   nbr13    = (const int*)  d_in[1];
    const int*   nbr31    = (const int*)  d_in[2];
    const float* w1       = (const float*)d_in[3];
    const float* w12      = (const float*)d_in[4];
    const float* w2       = (const float*)d_in[5];
    const float* w3       = (const float*)d_in[6];
    const float* gamma    = (const float*)d_in[7];  // [4][32]
    const float* beta     = (const float*)d_in[8];
    const float* mean     = (const float*)d_in[9];
    const float* var      = (const float*)d_in[10];
    float* out = (float*)d_out;

    const size_t tabShorts = (size_t)NPTS * 32;          // 25.6 MB per table
    unsigned short* sc1 = (unsigned short*)d_ws;
    unsigned short* tmn = sc1 + tabShorts;
    unsigned short* fb  = (unsigned short*)d_out;        // dead before convB writes

    unsigned short* pw  = nullptr;
    float*          sbf = nullptr;
    const size_t need = 2 * tabShorts * 2 + 28672 * 2 + 256 * 4;
    if (ws_size >= need) {
        pw  = tmn + tabShorts;
        sbf = (float*)(pw + 28672);
        pack_all<<<113, 256, 0, stream>>>(w1, w2, w12, w3, gamma, beta, mean, var, pw, sbf);
    }

    cvt_feat<<<(NPTS + 255) / 256, 256, 0, stream>>>(features, fb);

    dim3 grid(NTILES / 4), block(256);   // 6250 blocks, 1 tile per wave

    convA<<<grid, block, 0, stream>>>(fb, nbr13, nbr31, w1, w2, pw, sbf,
                                      gamma, beta, mean, var, sc1, tmn);
    convB<<<grid, block, 0, stream>>>(sc1, tmn, nbr13, nbr31, w12, w3, pw, sbf,
                                      gamma, beta, mean, var, out);
}

// Round 8
// 249.972 us; speedup vs baseline: 8.0298x; 1.0053x over previous
//
#include <hip/hip_runtime.h>

#define NPTS 400000
#define KTAPS 9
#define BN_EPS 1e-5f
#define NTILES (NPTS / 16)   // 25000 exact

typedef __attribute__((ext_vector_type(8))) short bf16x8;
typedef __attribute__((ext_vector_type(4))) float f32x4;

__device__ __forceinline__ unsigned short f2bf(float f) {
    union { float f; unsigned int i; } v; v.f = f;
    v.i += 0x7fffu + ((v.i >> 16) & 1u);   // round-to-nearest-even
    return (unsigned short)(v.i >> 16);
}

// ---- features f32 [N][16] -> bf16 [N][16] table ----
__global__ __launch_bounds__(256) void cvt_feat(const float* __restrict__ feat,
                                                unsigned short* __restrict__ fb) {
    int n = blockIdx.x * 256 + threadIdx.x;
    if (n >= NPTS) return;
    const float4* p = reinterpret_cast<const float4*>(feat + (size_t)n * 16);
    float4 a = p[0], b = p[1], c = p[2], d = p[3];
    float v[16] = {a.x,a.y,a.z,a.w, b.x,b.y,b.z,b.w,
                   c.x,c.y,c.z,c.w, d.x,d.y,d.z,d.w};
    unsigned int pk[8];
    #pragma unroll
    for (int j = 0; j < 8; ++j)
        pk[j] = (unsigned int)f2bf(v[2*j]) | ((unsigned int)f2bf(v[2*j+1]) << 16);
    uint4* o = reinterpret_cast<uint4*>(fb + (size_t)n * 16);
    o[0] = make_uint4(pk[0], pk[1], pk[2], pk[3]);
    o[1] = make_uint4(pk[4], pk[5], pk[6], pk[7]);
}

// ---- one-shot packer: 4 weight tables -> bf16 B-fragments, BN -> (s,b) ----
// pw (shorts): w1@0 (5120), w2@5120 (5120), w12@10240 (9216), w3@19456 (9216)
// sbf: [4][32] float2 flat, BN rows 0..3
__global__ __launch_bounds__(256) void pack_all(
    const float* __restrict__ w1, const float* __restrict__ w2,
    const float* __restrict__ w12, const float* __restrict__ w3,
    const float* __restrict__ gamma, const float* __restrict__ beta,
    const float* __restrict__ mean, const float* __restrict__ var,
    unsigned short* __restrict__ pw, float* __restrict__ sbf)
{
    int t = blockIdx.x * 256 + threadIdx.x;
    if (t < 28672) {
        const float* W; int CIN, f;
        if      (t < 5120)  { W = w1;  CIN = 16; f = t; }
        else if (t < 10240) { W = w2;  CIN = 16; f = t - 5120; }
        else if (t < 19456) { W = w12; CIN = 32; f = t - 10240; }
        else                { W = w3;  CIN = 32; f = t - 19456; }
        int j = f & 7, l = (f >> 3) & 63, fb = f >> 9;
        int g = fb >> 1, b = fb & 1;
        int kk = 8 * (l >> 4) + j;
        int tap, ch;
        if (CIN == 16) { tap = 2 * g + (kk >> 4); ch = kk & 15; }
        else           { tap = g;                 ch = kk;      }
        float w = (tap < KTAPS) ? W[((size_t)(tap * CIN + ch)) * 32 + b * 16 + (l & 15)] : 0.f;
        pw[t] = f2bf(w);
    } else if (t < 28672 + 128) {
        int r = t - 28672;
        float s  = gamma[r] * rsqrtf(var[r] + BN_EPS);
        float bb = beta[r] - mean[r] * s;
        sbf[2 * r]     = s;
        sbf[2 * r + 1] = bb;
    }
}

__device__ __forceinline__ uint4 gather16(const char* __restrict__ base, int id,
                                          int rowBytes, int boff) {
    int s = (id < NPTS) ? id : 0;
    uint4 v = *reinterpret_cast<const uint4*>(base + (size_t)s * rowBytes + boff);
    if (id >= NPTS) v = make_uint4(0u, 0u, 0u, 0u);
    return v;
}

// fallback in-kernel packer for one CIN=16 or CIN=32 table into LDS
__device__ __forceinline__ void pack_lds(unsigned short* Bp, const float* W,
                                         int CIN, int nshorts, int tid, int nthreads) {
    for (int f = tid; f < nshorts; f += nthreads) {
        int j = f & 7, l = (f >> 3) & 63, fb = f >> 9;
        int g = fb >> 1, b = fb & 1;
        int kk = 8 * (l >> 4) + j;
        int tap, ch;
        if (CIN == 16) { tap = 2 * g + (kk >> 4); ch = kk & 15; }
        else           { tap = g;                 ch = kk;      }
        float w = (tap < KTAPS) ? W[((size_t)(tap * CIN + ch)) * 32 + b * 16 + (l & 15)] : 0.f;
        Bp[f] = f2bf(w);
    }
}

// ---- Kernel A: conv1 (fb,nbr13,w1,BN0 -> sc1) + conv2 (fb,nbr31,w2,BN2 -> tmn) ----
// 512-thread blocks, 8 waves = 8 tiles/block; 10 gathers in flight per wave.
__global__ __launch_bounds__(512) void convA(
    const unsigned short* __restrict__ fb,
    const int* __restrict__ nbr13, const int* __restrict__ nbr31,
    const float* __restrict__ w1f, const float* __restrict__ w2f,
    const unsigned short* __restrict__ pW, const float* __restrict__ sbf,
    const float* __restrict__ gamma, const float* __restrict__ beta,
    const float* __restrict__ mean, const float* __restrict__ var,
    unsigned short* __restrict__ sc1, unsigned short* __restrict__ tmn)
{
    __shared__ __align__(16) unsigned short Bp[10240];  // w1 frags | w2 frags
    __shared__ float2 SB[64];                           // [0..31]=BN0, [32..63]=BN2

    const int tid  = threadIdx.x;
    const int lane = tid & 63;
    const int lrow = lane & 15, lgrp = lane >> 4;
    const int tile = blockIdx.x * 8 + (tid >> 6);
    const int tb   = tile * 16;
    const int prow = tb + lrow;

    int i13[KTAPS], i31[KTAPS];
    #pragma unroll
    for (int k = 0; k < KTAPS; ++k) i13[k] = nbr13[(size_t)prow * KTAPS + k];
    #pragma unroll
    for (int k = 0; k < KTAPS; ++k) i31[k] = nbr31[(size_t)prow * KTAPS + k];

    if (pW != nullptr) {
        // Bp = 10240 shorts = 1280 uint4
        #pragma unroll
        for (int i = tid; i < 1280; i += 512)
            reinterpret_cast<uint4*>(Bp)[i] = reinterpret_cast<const uint4*>(pW)[i];
        if (tid < 64)
            SB[tid] = reinterpret_cast<const float2*>(sbf)[(tid < 32) ? tid : tid + 32];
    } else {
        pack_lds(Bp, w1f, 16, 5120, tid, 512);
        pack_lds(Bp + 5120, w2f, 16, 5120, tid, 512);
        if (tid < 64) {
            int row = (tid < 32) ? 0 : 2, o = tid & 31;
            float s  = gamma[row*32+o] * rsqrtf(var[row*32+o] + BN_EPS);
            float bb = beta[row*32+o] - mean[row*32+o] * s;
            SB[tid] = make_float2(s, bb);
        }
    }
    __syncthreads();

    // 10 independent gathers (fb rows are 32B)
    uint4 g1[5], g2[5];
    #pragma unroll
    for (int q = 0; q < 5; ++q) {
        int tsel = 2 * q + (lgrp >> 1); if (tsel > 8) tsel = 8;
        int boff = (lgrp & 1) * 16;
        g1[q] = gather16((const char*)fb, i13[tsel], 32, boff);
        g2[q] = gather16((const char*)fb, i31[tsel], 32, boff);
    }

    f32x4 a10 = {0,0,0,0}, a11 = {0,0,0,0}, a20 = {0,0,0,0}, a21 = {0,0,0,0};
    #pragma unroll
    for (int q = 0; q < 5; ++q) {
        bf16x8 x1 = *reinterpret_cast<const bf16x8*>(&g1[q]);
        bf16x8 x2 = *reinterpret_cast<const bf16x8*>(&g2[q]);
        bf16x8 b10 = *reinterpret_cast<const bf16x8*>(&Bp[(2*q+0)*512 + lane*8]);
        bf16x8 b11 = *reinterpret_cast<const bf16x8*>(&Bp[(2*q+1)*512 + lane*8]);
        bf16x8 b20 = *reinterpret_cast<const bf16x8*>(&Bp[5120 + (2*q+0)*512 + lane*8]);
        bf16x8 b21 = *reinterpret_cast<const bf16x8*>(&Bp[5120 + (2*q+1)*512 + lane*8]);
        a10 = __builtin_amdgcn_mfma_f32_16x16x32_bf16(x1, b10, a10, 0, 0, 0);
        a11 = __builtin_amdgcn_mfma_f32_16x16x32_bf16(x1, b11, a11, 0, 0, 0);
        a20 = __builtin_amdgcn_mfma_f32_16x16x32_bf16(x2, b20, a20, 0, 0, 0);
        a21 = __builtin_amdgcn_mfma_f32_16x16x32_bf16(x2, b21, a21, 0, 0, 0);
    }

    #pragma unroll
    for (int b = 0; b < 2; ++b) {
        const int o = b * 16 + lrow;
        const float2 s0 = SB[o];        // BN row 0 (sc1)
        const float2 s2 = SB[32 + o];   // BN row 2 (tmn)
        const f32x4 v1 = (b == 0) ? a10 : a11;
        const f32x4 v2 = (b == 0) ? a20 : a21;
        #pragma unroll
        for (int r = 0; r < 4; ++r) {
            const int m = tb + 4 * lgrp + r;
            sc1[(size_t)m * 32 + o] = f2bf(fmaxf(fmaf(v1[r], s0.x, s0.y), 0.f));
            tmn[(size_t)m * 32 + o] = f2bf(fmaxf(fmaf(v2[r], s2.x, s2.y), 0.f));
        }
    }
}

// ---- Kernel B: out = BNReLU3(conv(tmn,nbr13,w3)) + BNReLU1(conv(sc1,nbr31,w12)) ----
// 512-thread blocks: LDS (37KB) shared by 8 waves -> 32 waves/CU (was 16).
// 18 gathers in flight per wave; residual added in-register (no RMW).
__global__ __launch_bounds__(512) void convB(
    const unsigned short* __restrict__ sc1, const unsigned short* __restrict__ tmn,
    const int* __restrict__ nbr13, const int* __restrict__ nbr31,
    const float* __restrict__ w12f, const float* __restrict__ w3f,
    const unsigned short* __restrict__ pW, const float* __restrict__ sbf,
    const float* __restrict__ gamma, const float* __restrict__ beta,
    const float* __restrict__ mean, const float* __restrict__ var,
    float* __restrict__ out)
{
    __shared__ __align__(16) unsigned short Bp[18432];  // w12 frags | w3 frags
    __shared__ float2 SB[64];                           // [0..31]=BN1, [32..63]=BN3

    const int tid  = threadIdx.x;
    const int lane = tid & 63;
    const int lrow = lane & 15, lgrp = lane >> 4;
    const int tile = blockIdx.x * 8 + (tid >> 6);
    const int tb   = tile * 16;
    const int prow = tb + lrow;

    int i13[KTAPS], i31[KTAPS];
    #pragma unroll
    for (int k = 0; k < KTAPS; ++k) i13[k] = nbr13[(size_t)prow * KTAPS + k];
    #pragma unroll
    for (int k = 0; k < KTAPS; ++k) i31[k] = nbr31[(size_t)prow * KTAPS + k];

    if (pW != nullptr) {
        // Bp = 18432 shorts = 2304 uint4
        #pragma unroll
        for (int i = tid; i < 2304; i += 512)
            reinterpret_cast<uint4*>(Bp)[i] =
                reinterpret_cast<const uint4*>(pW + 10240)[i];
        if (tid < 64)
            SB[tid] = reinterpret_cast<const float2*>(sbf)[32 + ((tid < 32) ? tid : tid + 32)];
    } else {
        pack_lds(Bp, w12f, 32, 9216, tid, 512);
        pack_lds(Bp + 9216, w3f, 32, 9216, tid, 512);
        if (tid < 64) {
            int row = (tid < 32) ? 1 : 3, o = tid & 31;
            float s  = gamma[row*32+o] * rsqrtf(var[row*32+o] + BN_EPS);
            float bb = beta[row*32+o] - mean[row*32+o] * s;
            SB[tid] = make_float2(s, bb);
        }
    }
    __syncthreads();

    // 18 independent gathers (table rows are 64B)
    const int boff = lgrp * 16;
    uint4 gs[KTAPS], gt[KTAPS];
    #pragma unroll
    for (int q = 0; q < KTAPS; ++q) gs[q] = gather16((const char*)sc1, i31[q], 64, boff);
    #pragma unroll
    for (int q = 0; q < KTAPS; ++q) gt[q] = gather16((const char*)tmn, i13[q], 64, boff);

    f32x4 s0 = {0,0,0,0}, s1 = {0,0,0,0}, t0 = {0,0,0,0}, t1 = {0,0,0,0};
    #pragma unroll
    for (int q = 0; q < KTAPS; ++q) {
        bf16x8 xs = *reinterpret_cast<const bf16x8*>(&gs[q]);
        bf16x8 xt = *reinterpret_cast<const bf16x8*>(&gt[q]);
        bf16x8 bs0 = *reinterpret_cast<const bf16x8*>(&Bp[(2*q+0)*512 + lane*8]);
        bf16x8 bs1 = *reinterpret_cast<const bf16x8*>(&Bp[(2*q+1)*512 + lane*8]);
        bf16x8 bt0 = *reinterpret_cast<const bf16x8*>(&Bp[9216 + (2*q+0)*512 + lane*8]);
        bf16x8 bt1 = *reinterpret_cast<const bf16x8*>(&Bp[9216 + (2*q+1)*512 + lane*8]);
        s0 = __builtin_amdgcn_mfma_f32_16x16x32_bf16(xs, bs0, s0, 0, 0, 0);
        s1 = __builtin_amdgcn_mfma_f32_16x16x32_bf16(xs, bs1, s1, 0, 0, 0);
        t0 = __builtin_amdgcn_mfma_f32_16x16x32_bf16(xt, bt0, t0, 0, 0, 0);
        t1 = __builtin_amdgcn_mfma_f32_16x16x32_bf16(xt, bt1, t1, 0, 0, 0);
    }

    #pragma unroll
    for (int b = 0; b < 2; ++b) {
        const int o = b * 16 + lrow;
        const float2 c1 = SB[o];        // BN row 1 (sc path, w12)
        const float2 c3 = SB[32 + o];   // BN row 3 (main path, w3)
        const f32x4 vs = (b == 0) ? s0 : s1;
        const f32x4 vt = (b == 0) ? t0 : t1;
        #pragma unroll
        for (int r = 0; r < 4; ++r) {
            const int m = tb + 4 * lgrp + r;
            float ys = fmaxf(fmaf(vs[r], c1.x, c1.y), 0.f);
            float yt = fmaxf(fmaf(vt[r], c3.x, c3.y), 0.f);
            out[(size_t)m * 32 + o] = ys + yt;
        }
    }
}

extern "C" void kernel_launch(void* const* d_in, const int* in_sizes, int n_in,
                              void* d_out, int out_size, void* d_ws, size_t ws_size,
                              hipStream_t stream) {
    const float* features = (const float*)d_in[0];
    const int*   nbr13    = (const int*)  d_in[1];
    const int*   nbr31    = (const int*)  d_in[2];
    const float* w1       = (const float*)d_in[3];
    const float* w12      = (const float*)d_in[4];
    const float* w2       = (const float*)d_in[5];
    const float* w3       = (const float*)d_in[6];
    const float* gamma    = (const float*)d_in[7];  // [4][32]
    const float* beta     = (const float*)d_in[8];
    const float* mean     = (const float*)d_in[9];
    const float* var      = (const float*)d_in[10];
    float* out = (float*)d_out;

    const size_t tabShorts = (size_t)NPTS * 32;          // 25.6 MB per table
    unsigned short* sc1 = (unsigned short*)d_ws;
    unsigned short* tmn = sc1 + tabShorts;
    unsigned short* fb  = (unsigned short*)d_out;        // dead before convB writes

    unsigned short* pw  = nullptr;
    float*          sbf = nullptr;
    const size_t need = 2 * tabShorts * 2 + 28672 * 2 + 256 * 4;
    if (ws_size >= need) {
        pw  = tmn + tabShorts;
        sbf = (float*)(pw + 28672);
        pack_all<<<113, 256, 0, stream>>>(w1, w2, w12, w3, gamma, beta, mean, var, pw, sbf);
    }

    cvt_feat<<<(NPTS + 255) / 256, 256, 0, stream>>>(features, fb);

    dim3 grid(NTILES / 8), block(512);   // 3125 blocks x 8 waves, 1 tile/wave

    convA<<<grid, block, 0, stream>>>(fb, nbr13, nbr31, w1, w2, pw, sbf,
                                      gamma, beta, mean, var, sc1, tmn);
    convB<<<grid, block, 0, stream>>>(sc1, tmn, nbr13, nbr31, w12, w3, pw, sbf,
                                      gamma, beta, mean, var, out);
}